// Round 3
// baseline (927.417 us; speedup 1.0000x reference)
//
#include <hip/hip_runtime.h>
#include <hip/hip_bf16.h>
#include <cstdint>

// GraphSAGEMean R3: 4 streaming GEMM kernels, weights register-resident per
// wave (64ch x 256k slice = 128 VGPRs), B-frags loaded directly from global
// (row-major bf16 act IS the B-frag layout), activations chained IN-PLACE
// through d_out's head region (bf16 [N,256] = 102.4MB, agg lives just past
// it). ws holds only the 448KB transposed bf16 weights. No LDS in the GEMM
// path; one __syncthreads per block (in-place safety) in K2-K4; none in K1.

#define N_ROWS 200000

typedef short bf16x8 __attribute__((ext_vector_type(8)));   // 8 bf16 = 4 VGPRs
typedef float f32x4  __attribute__((ext_vector_type(4)));

__device__ __forceinline__ unsigned short rne_bf16(float f) {
  unsigned int u = __float_as_uint(f);
  u += 0x7FFFu + ((u >> 16) & 1u);
  return (unsigned short)(u >> 16);
}

__device__ __forceinline__ bf16x8 pack8(f32x4 a, f32x4 c) {
  union { bf16x8 v; __hip_bfloat162 h[4]; } u;
  u.h[0] = __float22bfloat162_rn(make_float2(a[0], a[1]));
  u.h[1] = __float22bfloat162_rn(make_float2(a[2], a[3]));
  u.h[2] = __float22bfloat162_rn(make_float2(c[0], c[1]));
  u.h[3] = __float22bfloat162_rn(make_float2(c[2], c[3]));
  return u.v;
}

__device__ __forceinline__ ushort4 pack4(f32x4 v) {
  union { ushort4 s; __hip_bfloat162 h[2]; } u;
  u.h[0] = __float22bfloat162_rn(make_float2(v[0], v[1]));
  u.h[1] = __float22bfloat162_rn(make_float2(v[2], v[3]));
  return u.s;
}

// LDS-tiled transpose + bf16 cast: Wt[o][k] = bf16(W[k][o]).
// ws layout (ushort): Wt1 @0, Wt2 @65536, Wt3 @131072, Wto @196608.
__global__ __launch_bounds__(256) void prep_kernel(
    const float* __restrict__ W1, const float* __restrict__ W2,
    const float* __restrict__ W3, const float* __restrict__ Wo,
    unsigned short* __restrict__ wt) {
  __shared__ float tile[64][65];
  const int b = blockIdx.x;
  int which, tb;
  if (b < 48) { which = b >> 4; tb = b & 15; }
  else        { which = 3;      tb = b - 48; }
  const float* W = (which == 0) ? W1 : (which == 1) ? W2 : (which == 2) ? W3 : Wo;
  const int O = (which == 3) ? 128 : 256;
  unsigned short* out = wt + (size_t)which * 65536;
  const int otiles = O >> 6;
  const int r0 = (tb / otiles) * 64;
  const int c0 = (tb % otiles) * 64;
  const int j  = threadIdx.x & 63;
  const int ib = threadIdx.x >> 6;
#pragma unroll
  for (int ii = 0; ii < 16; ++ii) {
    const int i = ii * 4 + ib;
    tile[i][j] = W[(size_t)(r0 + i) * O + c0 + j];
  }
  __syncthreads();
#pragma unroll
  for (int ii = 0; ii < 16; ++ii) {
    const int i = ii * 4 + ib;
    out[(size_t)(c0 + i) * 256 + r0 + j] = rne_bf16(tile[j][i]);
  }
}

// K1: E (fp32) -> act1 (bf16, in d_out head) + agg (fp32, d_out tail).
// 64 rows/block, 4 groups of 16, 2-deep prefetch pipeline, no barriers.
__global__ __launch_bounds__(256, 2) void layer1_kernel(
    const float* __restrict__ E, const unsigned short* __restrict__ wt,
    const float* __restrict__ bias, unsigned short* act, float* out_agg) {
  const int t = threadIdx.x, wave = t >> 6, lane = t & 63;
  const int lc = lane & 15, quad = lane >> 4;
  const size_t row0 = (size_t)blockIdx.x * 64;
  const int m_base = wave * 64;
  const bool w0 = (wave == 0);

  bf16x8 afr[4][8];                       // full 64ch x 256k slice in regs
#pragma unroll
  for (int mb = 0; mb < 4; ++mb)
#pragma unroll
    for (int ks = 0; ks < 8; ++ks)
      afr[mb][ks] = *(const bf16x8*)&wt[(size_t)(m_base + mb * 16 + lc) * 256 + ks * 32 + 8 * quad];

  f32x4 bb[4];
#pragma unroll
  for (int mb = 0; mb < 4; ++mb)
    bb[mb] = *(const f32x4*)&bias[m_base + mb * 16 + 4 * quad];

  bf16x8 bfr[2][8];
  float s[2];

#define STAGE1(b, g) do {                                                     \
    float _sum = 0.f;                                                         \
    const float* _ep = E + (row0 + (size_t)(g) * 16 + lc) * 256 + 8 * quad;   \
    _Pragma("unroll")                                                         \
    for (int ks = 0; ks < 8; ++ks) {                                          \
      f32x4 _a = *(const f32x4*)(_ep + ks * 32);                              \
      f32x4 _c = *(const f32x4*)(_ep + ks * 32 + 4);                          \
      if (w0) _sum += _a[0]+_a[1]+_a[2]+_a[3]+_c[0]+_c[1]+_c[2]+_c[3];        \
      bfr[b][ks] = pack8(_a, _c);                                             \
    }                                                                         \
    s[b] = _sum;                                                              \
  } while (0)

  STAGE1(0, 0);
#pragma unroll
  for (int g = 0; g < 4; ++g) {
    if (g < 3) STAGE1((g + 1) & 1, g + 1);
    f32x4 acc[4] = {};
#pragma unroll
    for (int ks = 0; ks < 8; ++ks)
#pragma unroll
      for (int mb = 0; mb < 4; ++mb)
        acc[mb] = __builtin_amdgcn_mfma_f32_16x16x32_bf16(afr[mb][ks], bfr[g & 1][ks], acc[mb], 0, 0, 0);

    float sg = s[g & 1];                  // row-mean (output 1)
    sg += __shfl_xor(sg, 16);
    sg += __shfl_xor(sg, 32);
    if (w0 && lane < 16) out_agg[row0 + g * 16 + lane] = sg * (1.0f / 256.0f);

    const size_t r = row0 + g * 16 + lc;
#pragma unroll
    for (int mb = 0; mb < 4; ++mb) {
      f32x4 v = acc[mb] + bb[mb];
#pragma unroll
      for (int j = 0; j < 4; ++j) v[j] = fmaxf(v[j], 0.f);
      *(ushort4*)&act[r * 256 + m_base + mb * 16 + 4 * quad] = pack4(v);
    }
  }
#undef STAGE1
}

// K2/K3: act (bf16) -> act (bf16) IN-PLACE. 32 rows/block; stage both
// 16-row groups, one barrier, then MFMA + store. Weights in regs.
__global__ __launch_bounds__(256, 2) void layer_mid_kernel(
    unsigned short* act, const unsigned short* __restrict__ wt,
    const float* __restrict__ bias) {
  const int t = threadIdx.x, wave = t >> 6, lane = t & 63;
  const int lc = lane & 15, quad = lane >> 4;
  const size_t row0 = (size_t)blockIdx.x * 32;
  const int m_base = wave * 64;

  bf16x8 bfr[2][8];
#pragma unroll
  for (int g = 0; g < 2; ++g)
#pragma unroll
    for (int ks = 0; ks < 8; ++ks)
      bfr[g][ks] = *(const bf16x8*)&act[(row0 + g * 16 + lc) * 256 + ks * 32 + 8 * quad];

  bf16x8 afr[4][8];
#pragma unroll
  for (int mb = 0; mb < 4; ++mb)
#pragma unroll
    for (int ks = 0; ks < 8; ++ks)
      afr[mb][ks] = *(const bf16x8*)&wt[(size_t)(m_base + mb * 16 + lc) * 256 + ks * 32 + 8 * quad];

  f32x4 bb[4];
#pragma unroll
  for (int mb = 0; mb < 4; ++mb)
    bb[mb] = *(const f32x4*)&bias[m_base + mb * 16 + 4 * quad];

  __syncthreads();   // all reads of this block's rows done before in-place writes

#pragma unroll
  for (int g = 0; g < 2; ++g) {
    f32x4 acc[4] = {};
#pragma unroll
    for (int ks = 0; ks < 8; ++ks)
#pragma unroll
      for (int mb = 0; mb < 4; ++mb)
        acc[mb] = __builtin_amdgcn_mfma_f32_16x16x32_bf16(afr[mb][ks], bfr[g][ks], acc[mb], 0, 0, 0);
    const size_t r = row0 + g * 16 + lc;
#pragma unroll
    for (int mb = 0; mb < 4; ++mb) {
      f32x4 v = acc[mb] + bb[mb];
#pragma unroll
      for (int j = 0; j < 4; ++j) v[j] = fmaxf(v[j], 0.f);
      *(ushort4*)&act[r * 256 + m_base + mb * 16 + 4 * quad] = pack4(v);
    }
  }
}

// K4: act (bf16) -> out_x (fp32) IN-PLACE (row r bf16 [512r,512r+512) ->
// row r fp32 out, same bytes). 32 rows/block; waves 0,1 = ch 0-63/64-127 of
// group 0; waves 2,3 same for group 1. Stage, barrier, compute, store.
__global__ __launch_bounds__(256, 2) void layer_out_kernel(
    const unsigned short* actc, float* out_x,
    const unsigned short* __restrict__ wt, const float* __restrict__ bias) {
  const int t = threadIdx.x, wave = t >> 6, lane = t & 63;
  const int lc = lane & 15, quad = lane >> 4;
  const size_t row0 = (size_t)blockIdx.x * 32;
  const int m_base = (wave & 1) * 64;
  const int g = wave >> 1;
  const size_t r = row0 + g * 16 + lc;

  bf16x8 bfr[8];
#pragma unroll
  for (int ks = 0; ks < 8; ++ks)
    bfr[ks] = *(const bf16x8*)&actc[r * 256 + ks * 32 + 8 * quad];

  bf16x8 afr[4][8];
#pragma unroll
  for (int mb = 0; mb < 4; ++mb)
#pragma unroll
    for (int ks = 0; ks < 8; ++ks)
      afr[mb][ks] = *(const bf16x8*)&wt[(size_t)(m_base + mb * 16 + lc) * 256 + ks * 32 + 8 * quad];

  f32x4 bb[4];
#pragma unroll
  for (int mb = 0; mb < 4; ++mb)
    bb[mb] = *(const f32x4*)&bias[m_base + mb * 16 + 4 * quad];

  __syncthreads();   // all bf16 reads done before fp32 overwrite

  f32x4 acc[4] = {};
#pragma unroll
  for (int ks = 0; ks < 8; ++ks)
#pragma unroll
    for (int mb = 0; mb < 4; ++mb)
      acc[mb] = __builtin_amdgcn_mfma_f32_16x16x32_bf16(afr[mb][ks], bfr[ks], acc[mb], 0, 0, 0);

#pragma unroll
  for (int mb = 0; mb < 4; ++mb) {
    f32x4 v = acc[mb] + bb[mb];
    *(f32x4*)&out_x[r * 128 + m_base + mb * 16 + 4 * quad] = v;
  }
}

extern "C" void kernel_launch(void* const* d_in, const int* in_sizes, int n_in,
                              void* d_out, int out_size, void* d_ws, size_t ws_size,
                              hipStream_t stream) {
  const float* E  = (const float*)d_in[0];
  // d_in[1] = adj_keys: identity gather in reference, unused
  const float* W1 = (const float*)d_in[2];
  const float* b1 = (const float*)d_in[3];
  const float* W2 = (const float*)d_in[4];
  const float* b2 = (const float*)d_in[5];
  const float* W3 = (const float*)d_in[6];
  const float* b3 = (const float*)d_in[7];
  const float* Wo = (const float*)d_in[8];
  const float* bo = (const float*)d_in[9];

  unsigned short* wts    = (unsigned short*)d_ws;        // 448 KB
  unsigned short* actbuf = (unsigned short*)d_out;       // [N,256] bf16 = 102.4 MB
  float* out_x   = (float*)d_out;                        // final [N,128] fp32
  float* out_agg = out_x + (size_t)N_ROWS * 128;         // starts at byte 102.4e6

  prep_kernel<<<56, 256, 0, stream>>>(W1, W2, W3, Wo, wts);
  layer1_kernel  <<<N_ROWS / 64, 256, 0, stream>>>(E, wts, b1, actbuf, out_agg);
  layer_mid_kernel<<<N_ROWS / 32, 256, 0, stream>>>(actbuf, wts + 65536,  b2);
  layer_mid_kernel<<<N_ROWS / 32, 256, 0, stream>>>(actbuf, wts + 131072, b3);
  layer_out_kernel<<<N_ROWS / 32, 256, 0, stream>>>(actbuf, out_x, wts + 196608, bo);
}